// Round 17
// baseline (76.150 us; speedup 1.0000x reference)
//
#include <hip/hip_runtime.h>
#include <math.h>

// DigitalGCN: B=16, N=1024, D=128, 2 iters, fp32 in/out.
// out = relu(nsadj + inv*( (G0@x) + Vtot )), nsadj = NS + b_self - inv*v,
//   x = nm*w*(NL-NR), v = nm*w*NR, inv = nm/max(nm*(S-nm),1), G0 = G diag-cleared.
// Round 17 = r16 verified base (60.7us) with ONE change: wpack folded into
// pack_prep (blocks 0..12 build W tables / mask sums, then continue packing;
// prep blocks spin on the r11-validated acquire flag — satisfied ~instantly
// since pack dispatches first). 3 dispatches total. agg kernels r16-verbatim.

constexpr int B = 16, N = 1024, D = 128, ITERS = 2;

typedef unsigned short u16;
typedef unsigned char u8;
typedef unsigned int u32;
typedef __attribute__((ext_vector_type(8))) short short8v;
typedef __attribute__((ext_vector_type(4))) unsigned int uint4v;
typedef __attribute__((ext_vector_type(4))) float float4v;

__device__ inline u16 f32_to_bf16(float f) {
  u32 bits = __float_as_uint(f);
  bits += 0x7FFFu + ((bits >> 16) & 1u);  // RNE
  return (u16)(bits >> 16);
}

__device__ __forceinline__ short8v expand_byte(u32 by) {
  u32 e0 = ((by & 1u) ? 0x3F80u : 0u) | ((by & 2u) ? 0x3F800000u : 0u);
  u32 e1 = ((by & 4u) ? 0x3F80u : 0u) | ((by & 8u) ? 0x3F800000u : 0u);
  u32 e2 = ((by & 16u) ? 0x3F80u : 0u) | ((by & 32u) ? 0x3F800000u : 0u);
  u32 e3 = ((by & 64u) ? 0x3F80u : 0u) | ((by & 128u) ? 0x3F800000u : 0u);
  uint4v ev = {e0, e1, e2, e3};
  return __builtin_bit_cast(short8v, ev);
}

// XCD-aligned (b, rt16) for 1024-block prep (r12-verified).
__device__ __forceinline__ void map_brt(int blk, int& b, int& rt) {
  int slot = blk >> 3;
  b = ((slot >> 6) << 3) | (blk & 7);
  rt = slot & 63;
}

// XCD-aligned (b, rt32) for the 512-block agg kernels (r16-verified).
__device__ __forceinline__ void map_brt32(int blk, int& b, int& rt32) {
  int slot = blk >> 3;
  b = ((slot >> 5) << 3) | (blk & 7);
  rt32 = slot & 31;
}

// bounded spin until *p >= v (r11/r13-validated producer-consumer wait)
__device__ __forceinline__ void spin_ge(u32* p, u32 v) {
  int t = 0;
  while (__hip_atomic_load(p, __ATOMIC_ACQUIRE, __HIP_MEMORY_SCOPE_AGENT) < v) {
    __builtin_amdgcn_s_sleep(1);
    if (++t > (1 << 22)) break;
  }
}

// prep body (verified r7-r16): nlds[16][132] = 16 node rows; emits node_weight,
// nsadj, fragment-major xF, per-tile v partials. 256-thread semantics.
__device__ __forceinline__ void prep_body(
    float (*nlds)[132], float* wmrow, float* invrow, int b, int rt, int tid,
    const int* __restrict__ mask, const float* __restrict__ w_weight,
    const float* __restrict__ b_weight, const float* __restrict__ b_self,
    const u16* __restrict__ wsF, const u16* __restrict__ wlF,
    const u16* __restrict__ wrF, const float* __restrict__ sb,
    float* __restrict__ outw_t, float* __restrict__ nsadj, u16* __restrict__ xF,
    float* __restrict__ part) {
  int r0 = rt * 16;
  if (tid < 128) {  // node_weight: 8 threads/row, fp32
    int r = tid >> 3, jj = tid & 7;
    float acc = 0.f;
#pragma unroll
    for (int q = 0; q < 4; ++q) {
      float4 wv = *(const float4*)(w_weight + jj * 16 + q * 4);
      const float* np = &nlds[r][jj * 16 + q * 4];
      acc += np[0] * wv.x + np[1] * wv.y + np[2] * wv.z + np[3] * wv.w;
    }
    acc += __shfl_xor(acc, 4, 8);
    acc += __shfl_xor(acc, 2, 8);
    acc += __shfl_xor(acc, 1, 8);
    if (jj == 0) {
      float w = 1.f / (1.f + expf(-(acc + b_weight[0])));
      outw_t[b * (ITERS * N) + r0 + r] = w;
      float nm = (float)mask[b * N + r0 + r];
      float nnum = fmaxf(nm * (sb[b] - nm), 1.f);
      wmrow[r] = w * nm;
      invrow[r] = nm / nnum;
    }
  }
  __syncthreads();

  int w = tid >> 6, lane = tid & 63;
  int l15 = lane & 15, lg = lane >> 4;
  int ch = w * 32;

  short8v af[4];
#pragma unroll
  for (int ks = 0; ks < 4; ++ks) {
    float tmp[8];
    *(float4*)&tmp[0] = *(const float4*)&nlds[l15][ks * 32 + lg * 8];
    *(float4*)&tmp[4] = *(const float4*)&nlds[l15][ks * 32 + lg * 8 + 4];
    short8v t;
#pragma unroll
    for (int e = 0; e < 8; ++e) t[e] = (short)f32_to_bf16(tmp[e]);
    af[ks] = t;
  }

  float4v aNR[2], aNL[2], aNS[2];
#define RUN_GEMM(WF, ACC)                                                          \
  {                                                                                \
    _Pragma("unroll") for (int cf = 0; cf < 2; ++cf) {                             \
      ACC[cf] = (float4v){0.f, 0.f, 0.f, 0.f};                                     \
      int cblk = w * 2 + cf;                                                       \
      const u16* bp = (WF) + (((cblk * 4) * 64 + lane) << 3);                      \
      _Pragma("unroll") for (int ks = 0; ks < 4; ++ks) {                           \
        short8v bf = *(const short8v*)(bp + ks * 512);                             \
        ACC[cf] =                                                                  \
            __builtin_amdgcn_mfma_f32_16x16x32_bf16(af[ks], bf, ACC[cf], 0, 0, 0); \
      }                                                                            \
    }                                                                              \
  }
  RUN_GEMM(wrF, aNR);
  RUN_GEMM(wlF, aNL);
  RUN_GEMM(wsF, aNS);
#undef RUN_GEMM

  float wmv[4], invv[4];
#pragma unroll
  for (int j = 0; j < 4; ++j) {
    int rloc = lg * 4 + j;
    wmv[j] = wmrow[rloc];
    invv[j] = invrow[rloc];
  }
  int kch = rt >> 1;
  int lane_f = ((rt & 1) * 2 + (lg >> 1)) * 16;
  int e0 = (lg & 1) * 4;
  float pv[2] = {0.f, 0.f};
#pragma unroll
  for (int cf = 0; cf < 2; ++cf) {
    int col = ch + cf * 16 + l15;
    float bsv = b_self[col];
    u16 xb[4];
#pragma unroll
    for (int j = 0; j < 4; ++j) {
      float x = wmv[j] * (aNL[cf][j] - aNR[cf][j]);
      float v = wmv[j] * aNR[cf][j];
      pv[cf] += v;
      nsadj[((size_t)b * N + r0 + lg * 4 + j) * D + col] =
          aNS[cf][j] + bsv - invv[j] * v;
      xb[j] = f32_to_bf16(x);
    }
    int cblk = w * 2 + cf;
    size_t fi = ((((size_t)b * 8 + cblk) * 32 + kch) * 64 + lane_f + l15) * 8 + e0;
    *(ushort4*)&xF[fi] = *(ushort4*)&xb[0];
  }
#pragma unroll
  for (int cf = 0; cf < 2; ++cf) {
    pv[cf] += __shfl_xor(pv[cf], 16);
    pv[cf] += __shfl_xor(pv[cf], 32);
  }
  if (lg == 0) {
#pragma unroll
    for (int cf = 0; cf < 2; ++cf)
      part[((size_t)b * 64 + rt) * 128 + ch + cf * 16 + l15] = pv[cf];
  }
}

// agg core (r16-verified): 32 rows x 128 cols per block, 512 threads. Wave wv =
// cf slice x FULL K x 2 row-sets; acc in regs; depth-2 B prefetch.
__device__ __forceinline__ void agg32_core(
    const u8* __restrict__ gpk, const u16* __restrict__ xF,
    const float* __restrict__ part, const float* __restrict__ sb,
    const int* __restrict__ mask, const float* __restrict__ nsadj, int b, int r0,
    int tid, float (*red)[128], float ov[8]) {
  {  // Vtot partials: 512 threads, 4 groups x 16 part-rows
    int col = tid & 127, grp = tid >> 7;
    float s = 0.f;
#pragma unroll
    for (int p = 0; p < 16; ++p)
      s += part[((size_t)b * 64 + grp * 16 + p) * 128 + col];
    red[grp][col] = s;
  }
  int wv = tid >> 6, lane = tid & 63;
  int l15 = lane & 15, lg = lane >> 4;

  const u8* g0 = gpk + ((size_t)b * N + r0 + l15) * 128 + lg * 32;
  uint4 qA = *(const uint4*)g0;
  uint4 qB = *(const uint4*)(g0 + 16);
  uint4 qC = *(const uint4*)(g0 + 16 * 128);
  uint4 qD = *(const uint4*)(g0 + 16 * 128 + 16);
  u32 q0[8] = {qA.x, qA.y, qA.z, qA.w, qB.x, qB.y, qB.z, qB.w};
  u32 q1[8] = {qC.x, qC.y, qC.z, qC.w, qD.x, qD.y, qD.z, qD.w};

  const u16* xb = xF + (((size_t)b * 8 + wv) * 32) * 512 + lane * 8;

  float4v acc0 = {0.f, 0.f, 0.f, 0.f};
  float4v acc1 = {0.f, 0.f, 0.f, 0.f};
  short8v b0 = *(const short8v*)(xb);
  short8v b1 = *(const short8v*)(xb + 512);
#pragma unroll
  for (int cl = 0; cl < 32; ++cl) {
    short8v b2 = b0;  // placeholder for tail iterations
    if (cl + 2 < 32) b2 = *(const short8v*)(xb + (cl + 2) * 512);
    u32 by0 = (q0[cl >> 2] >> ((cl & 3) * 8)) & 255u;
    u32 by1 = (q1[cl >> 2] >> ((cl & 3) * 8)) & 255u;
    short8v a0 = expand_byte(by0);
    short8v a1 = expand_byte(by1);
    acc0 = __builtin_amdgcn_mfma_f32_16x16x32_bf16(a0, b0, acc0, 0, 0, 0);
    acc1 = __builtin_amdgcn_mfma_f32_16x16x32_bf16(a1, b0, acc1, 0, 0, 0);
    b0 = b1;
    b1 = b2;
  }
  __syncthreads();  // red ready for epilogue

  float sbv = sb[b];
  int col = wv * 16 + l15;
  float vt = red[0][col] + red[1][col] + red[2][col] + red[3][col];
#pragma unroll
  for (int rs = 0; rs < 2; ++rs) {
#pragma unroll
    for (int j = 0; j < 4; ++j) {
      float a = (rs == 0) ? acc0[j] : acc1[j];
      int orow = r0 + rs * 16 + lg * 4 + j;
      float nm = (float)mask[b * N + orow];
      float nnum = fmaxf(nm * (sbv - nm), 1.f);
      float inv = nm / nnum;
      size_t off = ((size_t)b * N + orow) * D + col;
      ov[rs * 4 + j] = fmaxf(nsadj[off] + inv * (a + vt), 0.f);
    }
  }
}

// Co-dispatched, 3072 blocks:
//  blocks 0..2047: graph bit-pack (hoisted loads). Blocks 0..11 first build one
//    W fragment table each; block 12 does mask sums; then they flag + pack.
//  blocks 2048..3071: prep t=0 (spin on flag after nlds staging; ~zero wait).
__global__ __launch_bounds__(256, 4) void pack_prep_kernel(
    const float* __restrict__ node, const int* __restrict__ graph,
    const int* __restrict__ mask, const float* __restrict__ w_weight,
    const float* __restrict__ b_weight, const float* __restrict__ b_self,
    const float* __restrict__ w_self, const float* __restrict__ w_left,
    const float* __restrict__ w_right, u16* __restrict__ wsF,
    u16* __restrict__ wlF, u16* __restrict__ wrF, float* __restrict__ sb,
    u8* __restrict__ gpk, float* __restrict__ outw, float* __restrict__ nsadjA,
    u16* __restrict__ xFA, float* __restrict__ partA, u32* bar) {
  __shared__ float nlds[16][132];
  __shared__ float wmrow[16], invrow[16];
  int tid = threadIdx.x;
  int blk = blockIdx.x;

  if (blk < 2048) {  // ---- pack role (with setup prologue in blocks 0..12)
    if (blk < 13) {
      if (blk < 12) {
        int widx = blk >> 2, seg = blk & 3;
        const float* W = (widx == 0) ? w_self : (widx == 1) ? w_left : w_right;
        u16* WF = (widx == 0) ? wsF : (widx == 1) ? wlF : wrF;
#pragma unroll
        for (int q = 0; q < 16; ++q) {
          int o = seg * 4096 + q * 256 + tid;  // frag-major output index
          int e = o & 7, lane = (o >> 3) & 63, ks = (o >> 9) & 3, cblk = o >> 11;
          int c = cblk * 16 + (lane & 15);
          int k = ks * 32 + ((lane >> 4) & 3) * 8 + e;
          WF[o] = f32_to_bf16(W[k * 128 + c]);
        }
      } else {
        int bb = tid >> 4, seg = tid & 15;
        const int* mp = mask + bb * N + seg * 64;
        int s = 0;
        for (int q = 0; q < 64; ++q) s += mp[q];
        float fs = (float)s;
        fs += __shfl_xor(fs, 8, 16);
        fs += __shfl_xor(fs, 4, 16);
        fs += __shfl_xor(fs, 2, 16);
        fs += __shfl_xor(fs, 1, 16);
        if (seg == 0) sb[bb] = fs;
      }
      __threadfence();
      __syncthreads();
      if (tid == 0)
        __hip_atomic_fetch_add(&bar[0], 1u, __ATOMIC_ACQ_REL,
                               __HIP_MEMORY_SCOPE_AGENT);
    }
    // pack: all loads issued before any store
    int gidx0 = blk * 256 + tid;
    int4 ra[4][2];
#pragma unroll
    for (int it = 0; it < 4; ++it) {
      int gidx = gidx0 + it * (2048 * 256);
      int j = gidx & 127, rowg = gidx >> 7;
      const int* gp = graph + ((size_t)rowg << 10) + j * 8;
      ra[it][0] = *(const int4*)gp;
      ra[it][1] = *(const int4*)(gp + 4);
    }
#pragma unroll
    for (int it = 0; it < 4; ++it) {
      int gidx = gidx0 + it * (2048 * 256);
      int j = gidx & 127, rowg = gidx >> 7;
      int i = rowg & (N - 1);
      int4 a = ra[it][0], c = ra[it][1];
      u32 by = (u32)(a.x != 0) | ((u32)(a.y != 0) << 1) | ((u32)(a.z != 0) << 2) |
               ((u32)(a.w != 0) << 3) | ((u32)(c.x != 0) << 4) |
               ((u32)(c.y != 0) << 5) | ((u32)(c.z != 0) << 6) |
               ((u32)(c.w != 0) << 7);
      if (j == (i >> 3)) by &= ~(1u << (i & 7));  // clear diagonal
      gpk[((size_t)rowg << 7) + (j & 3) * 32 + (j >> 2)] = (u8)by;
    }
    return;
  }

  int pblk = blk - 2048;  // 2048 % 8 == 0 -> XCD alignment preserved
  int b, rt;
  map_brt(pblk, b, rt);
  int r0 = rt * 16;

  const float* nbase = node + ((size_t)b * N + r0) * D;
#pragma unroll
  for (int p = 0; p < 2; ++p) {
    int g = p * 256 + tid;
    int row = g >> 5, c4 = g & 31;
    *(float4*)&nlds[row][c4 * 4] = *(const float4*)(nbase + row * 128 + c4 * 4);
  }
  if (tid == 0) spin_ge(&bar[0], 13);  // W tables + sb ready (~instant)
  __syncthreads();

  prep_body(nlds, wmrow, invrow, b, rt, tid, mask, w_weight, b_weight, b_self, wsF,
            wlF, wrF, sb, outw, nsadjA, xFA, partA);
}

// agg t=0 (A buffers) + prep t=1 (B buffers); out0 only in LDS. r16-verbatim.
__global__ __launch_bounds__(512, 4) void agg_prep_kernel(
    const u8* __restrict__ gpk, const int* __restrict__ mask,
    const float* __restrict__ w_weight, const float* __restrict__ b_weight,
    const float* __restrict__ b_self, const u16* __restrict__ wsF,
    const u16* __restrict__ wlF, const u16* __restrict__ wrF,
    const float* __restrict__ sb, const float* __restrict__ nsadjA,
    const u16* __restrict__ xFA, const float* __restrict__ partA,
    float* __restrict__ outw, float* __restrict__ nsadjB, u16* __restrict__ xFB,
    float* __restrict__ partB) {
  __shared__ float red[4][128];     // 2 KB
  __shared__ float nlds[32][132];   // 16.9 KB
  __shared__ float wmrow[32], invrow[32];
  int tid = threadIdx.x;
  int b, rt32;
  map_brt32(blockIdx.x, b, rt32);
  int r0 = rt32 * 32;

  float ov[8];
  agg32_core(gpk, xFA, partA, sb, mask, nsadjA, b, r0, tid, red, ov);

  int wv = tid >> 6, lane = tid & 63;
  int l15 = lane & 15, lg = lane >> 4;
  int col = wv * 16 + l15;
#pragma unroll
  for (int rs = 0; rs < 2; ++rs)
#pragma unroll
    for (int j = 0; j < 4; ++j) nlds[rs * 16 + lg * 4 + j][col] = ov[rs * 4 + j];
  __syncthreads();

  int half = tid >> 8;   // 0 or 1: which 16-row tile this half-block preps
  int tid2 = tid & 255;
  prep_body((float(*)[132]) & nlds[half * 16][0], &wmrow[half * 16],
            &invrow[half * 16], b, rt32 * 2 + half, tid2, mask, w_weight,
            b_weight, b_self, wsF, wlF, wrF, sb, outw + N, nsadjB, xFB, partB);
}

// agg t=1 -> final out. r16-verbatim.
__global__ __launch_bounds__(512, 4) void agg_fin_kernel(
    const u8* __restrict__ gpk, const int* __restrict__ mask,
    const float* __restrict__ sb, const float* __restrict__ nsadjB,
    const u16* __restrict__ xFB, const float* __restrict__ partB,
    float* __restrict__ out) {
  __shared__ float red[4][128];
  int tid = threadIdx.x;
  int b, rt32;
  map_brt32(blockIdx.x, b, rt32);
  int r0 = rt32 * 32;

  float ov[8];
  agg32_core(gpk, xFB, partB, sb, mask, nsadjB, b, r0, tid, red, ov);

  int wv = tid >> 6, lane = tid & 63;
  int l15 = lane & 15, lg = lane >> 4;
  int col = wv * 16 + l15;
#pragma unroll
  for (int rs = 0; rs < 2; ++rs)
#pragma unroll
    for (int j = 0; j < 4; ++j) {
      int orow = r0 + rs * 16 + lg * 4 + j;
      out[((size_t)b * N + orow) * D + col] = ov[rs * 4 + j];
    }
}

extern "C" void kernel_launch(void* const* d_in, const int* in_sizes, int n_in,
                              void* d_out, int out_size, void* d_ws, size_t ws_size,
                              hipStream_t stream) {
  const float* node0 = (const float*)d_in[0];
  const int* mask = (const int*)d_in[1];
  const int* graph = (const int*)d_in[2];
  const float* w_weight = (const float*)d_in[3];
  const float* b_weight = (const float*)d_in[4];
  const float* w_self = (const float*)d_in[5];
  const float* b_self = (const float*)d_in[6];
  const float* w_left = (const float*)d_in[7];
  const float* w_right = (const float*)d_in[8];
  float* out = (float*)d_out;
  float* outw = out + (size_t)B * N * D;  // all_node_weight [B,2,N]

  char* ws = (char*)d_ws;
  const size_t MB = 1024 * 1024;
  float* nsadjA = (float*)ws;                  // 8 MB
  float* nsadjB = (float*)(ws + 8 * MB);       // 8 MB
  u16* xFA = (u16*)(ws + 16 * MB);             // 4 MB
  u16* xFB = (u16*)(ws + 20 * MB);             // 4 MB
  u8* gpk = (u8*)(ws + 24 * MB);               // 2 MB
  u16* wsF = (u16*)(ws + 26 * MB);             // 3 x 32 KB
  u16* wlF = wsF + 16384;
  u16* wrF = wlF + 16384;
  float* partA = (float*)(ws + 26 * MB + 3 * 32768);  // 512 KB
  float* partB = partA + (size_t)B * 64 * 128;        // 512 KB
  float* sb = partB + (size_t)B * 64 * 128;           // 64 B
  u32* bar = (u32*)(ws + 28 * MB);                    // 64 B, zeroed each call

  hipMemsetAsync(bar, 0, 64, stream);
  pack_prep_kernel<<<3072, 256, 0, stream>>>(
      node0, graph, mask, w_weight, b_weight, b_self, w_self, w_left, w_right,
      wsF, wlF, wrF, sb, gpk, outw, nsadjA, xFA, partA, bar);
  agg_prep_kernel<<<512, 512, 0, stream>>>(gpk, mask, w_weight, b_weight, b_self,
                                           wsF, wlF, wrF, sb, nsadjA, xFA, partA,
                                           outw, nsadjB, xFB, partB);
  agg_fin_kernel<<<512, 512, 0, stream>>>(gpk, mask, sb, nsadjB, xFB, partB, out);
}

// Round 18
// 60.650 us; speedup vs baseline: 1.2556x; 1.2556x over previous
//
#include <hip/hip_runtime.h>
#include <math.h>

// DigitalGCN: B=16, N=1024, D=128, 2 iters, fp32 in/out.
// out = relu(nsadj + inv*( (G0@x) + Vtot )), nsadj = NS + b_self - inv*v,
//   x = nm*w*(NL-NR), v = nm*w*NR, inv = nm/max(nm*(S-nm),1), G0 = G diag-cleared.
// Round 18 = EXACT revert to round-16 verified best (60.7us). r17's wpack-merge
// regressed (76us): the pack stream wants plain dedicated blocks in a plain
// dispatch (r13/r14/r17 all confirmed). Locked configuration:
//  - wpack (13 blocks): W fragment tables + mask sums
//  - pack_prep (3072): 2048 grid-stride pack blocks + 1024 prep-t0 blocks
//  - agg_prep (512 x 512thr): agg-t0 (B-reuse core) + prep-t1, out0 in LDS only
//  - agg_fin (512 x 512thr): agg-t1 -> out
// Key verified techniques: 1-bit graph pack (diag-cleared, frag-permuted),
// fragment-major xF/wF (coalesced MFMA B-loads), bf16 MFMA with fp32 accum,
// VALU bit->bf16 A-expansion, XCD-aligned (b,rt) mapping, depth-2 B prefetch,
// wave-owns-full-K agg (B-reuse x2, no accbuf/no mid-loop barriers).

constexpr int B = 16, N = 1024, D = 128, ITERS = 2;

typedef unsigned short u16;
typedef unsigned char u8;
typedef unsigned int u32;
typedef __attribute__((ext_vector_type(8))) short short8v;
typedef __attribute__((ext_vector_type(4))) unsigned int uint4v;
typedef __attribute__((ext_vector_type(4))) float float4v;

__device__ inline u16 f32_to_bf16(float f) {
  u32 bits = __float_as_uint(f);
  bits += 0x7FFFu + ((bits >> 16) & 1u);  // RNE
  return (u16)(bits >> 16);
}

__device__ __forceinline__ short8v expand_byte(u32 by) {
  u32 e0 = ((by & 1u) ? 0x3F80u : 0u) | ((by & 2u) ? 0x3F800000u : 0u);
  u32 e1 = ((by & 4u) ? 0x3F80u : 0u) | ((by & 8u) ? 0x3F800000u : 0u);
  u32 e2 = ((by & 16u) ? 0x3F80u : 0u) | ((by & 32u) ? 0x3F800000u : 0u);
  u32 e3 = ((by & 64u) ? 0x3F80u : 0u) | ((by & 128u) ? 0x3F800000u : 0u);
  uint4v ev = {e0, e1, e2, e3};
  return __builtin_bit_cast(short8v, ev);
}

// XCD-aligned (b, rt16) for 1024-block prep (r12-verified).
__device__ __forceinline__ void map_brt(int blk, int& b, int& rt) {
  int slot = blk >> 3;
  b = ((slot >> 6) << 3) | (blk & 7);
  rt = slot & 63;
}

// blocks 0..11: W fragment tables. block 12: per-batch mask sums.
__global__ __launch_bounds__(256) void wpack_kernel(
    const float* __restrict__ w_self, const float* __restrict__ w_left,
    const float* __restrict__ w_right, const int* __restrict__ mask,
    u16* __restrict__ wsF, u16* __restrict__ wlF, u16* __restrict__ wrF,
    float* __restrict__ sb) {
  int blk = blockIdx.x, tid = threadIdx.x;
  if (blk < 12) {
    int widx = blk >> 2, seg = blk & 3;
    const float* W = (widx == 0) ? w_self : (widx == 1) ? w_left : w_right;
    u16* WF = (widx == 0) ? wsF : (widx == 1) ? wlF : wrF;
#pragma unroll
    for (int q = 0; q < 16; ++q) {
      int o = seg * 4096 + q * 256 + tid;
      int e = o & 7, lane = (o >> 3) & 63, ks = (o >> 9) & 3, cblk = o >> 11;
      int c = cblk * 16 + (lane & 15);
      int k = ks * 32 + ((lane >> 4) & 3) * 8 + e;
      WF[o] = f32_to_bf16(W[k * 128 + c]);
    }
  } else {
    int b = tid >> 4, seg = tid & 15;
    const int* mp = mask + b * N + seg * 64;
    int s = 0;
    for (int q = 0; q < 64; ++q) s += mp[q];
    float fs = (float)s;
    fs += __shfl_xor(fs, 8, 16);
    fs += __shfl_xor(fs, 4, 16);
    fs += __shfl_xor(fs, 2, 16);
    fs += __shfl_xor(fs, 1, 16);
    if (seg == 0) sb[b] = fs;
  }
}

// prep body (verified r7-r16): nlds[16][132] = 16 node rows; 256-thread
// semantics (callable from 512-thread blocks with tid=tid&255, split wm/inv).
__device__ __forceinline__ void prep_body(
    float (*nlds)[132], float* wmrow, float* invrow, int b, int rt, int tid,
    const int* __restrict__ mask, const float* __restrict__ w_weight,
    const float* __restrict__ b_weight, const float* __restrict__ b_self,
    const u16* __restrict__ wsF, const u16* __restrict__ wlF,
    const u16* __restrict__ wrF, const float* __restrict__ sb,
    float* __restrict__ outw_t, float* __restrict__ nsadj, u16* __restrict__ xF,
    float* __restrict__ part) {
  int r0 = rt * 16;
  if (tid < 128) {  // node_weight: 8 threads/row, fp32
    int r = tid >> 3, jj = tid & 7;
    float acc = 0.f;
#pragma unroll
    for (int q = 0; q < 4; ++q) {
      float4 wv = *(const float4*)(w_weight + jj * 16 + q * 4);
      const float* np = &nlds[r][jj * 16 + q * 4];
      acc += np[0] * wv.x + np[1] * wv.y + np[2] * wv.z + np[3] * wv.w;
    }
    acc += __shfl_xor(acc, 4, 8);
    acc += __shfl_xor(acc, 2, 8);
    acc += __shfl_xor(acc, 1, 8);
    if (jj == 0) {
      float w = 1.f / (1.f + expf(-(acc + b_weight[0])));
      outw_t[b * (ITERS * N) + r0 + r] = w;
      float nm = (float)mask[b * N + r0 + r];
      float nnum = fmaxf(nm * (sb[b] - nm), 1.f);
      wmrow[r] = w * nm;
      invrow[r] = nm / nnum;
    }
  }
  __syncthreads();

  int w = tid >> 6, lane = tid & 63;
  int l15 = lane & 15, lg = lane >> 4;
  int ch = w * 32;

  short8v af[4];
#pragma unroll
  for (int ks = 0; ks < 4; ++ks) {
    float tmp[8];
    *(float4*)&tmp[0] = *(const float4*)&nlds[l15][ks * 32 + lg * 8];
    *(float4*)&tmp[4] = *(const float4*)&nlds[l15][ks * 32 + lg * 8 + 4];
    short8v t;
#pragma unroll
    for (int e = 0; e < 8; ++e) t[e] = (short)f32_to_bf16(tmp[e]);
    af[ks] = t;
  }

  float4v aNR[2], aNL[2], aNS[2];
#define RUN_GEMM(WF, ACC)                                                          \
  {                                                                                \
    _Pragma("unroll") for (int cf = 0; cf < 2; ++cf) {                             \
      ACC[cf] = (float4v){0.f, 0.f, 0.f, 0.f};                                     \
      int cblk = w * 2 + cf;                                                       \
      const u16* bp = (WF) + (((cblk * 4) * 64 + lane) << 3);                      \
      _Pragma("unroll") for (int ks = 0; ks < 4; ++ks) {                           \
        short8v bf = *(const short8v*)(bp + ks * 512);                             \
        ACC[cf] =                                                                  \
            __builtin_amdgcn_mfma_f32_16x16x32_bf16(af[ks], bf, ACC[cf], 0, 0, 0); \
      }                                                                            \
    }                                                                              \
  }
  RUN_GEMM(wrF, aNR);
  RUN_GEMM(wlF, aNL);
  RUN_GEMM(wsF, aNS);
#undef RUN_GEMM

  float wmv[4], invv[4];
#pragma unroll
  for (int j = 0; j < 4; ++j) {
    int rloc = lg * 4 + j;
    wmv[j] = wmrow[rloc];
    invv[j] = invrow[rloc];
  }
  int kch = rt >> 1;
  int lane_f = ((rt & 1) * 2 + (lg >> 1)) * 16;
  int e0 = (lg & 1) * 4;
  float pv[2] = {0.f, 0.f};
#pragma unroll
  for (int cf = 0; cf < 2; ++cf) {
    int col = ch + cf * 16 + l15;
    float bsv = b_self[col];
    u16 xb[4];
#pragma unroll
    for (int j = 0; j < 4; ++j) {
      float x = wmv[j] * (aNL[cf][j] - aNR[cf][j]);
      float v = wmv[j] * aNR[cf][j];
      pv[cf] += v;
      nsadj[((size_t)b * N + r0 + lg * 4 + j) * D + col] =
          aNS[cf][j] + bsv - invv[j] * v;
      xb[j] = f32_to_bf16(x);
    }
    int cblk = w * 2 + cf;
    size_t fi = ((((size_t)b * 8 + cblk) * 32 + kch) * 64 + lane_f + l15) * 8 + e0;
    *(ushort4*)&xF[fi] = *(ushort4*)&xb[0];
  }
#pragma unroll
  for (int cf = 0; cf < 2; ++cf) {
    pv[cf] += __shfl_xor(pv[cf], 16);
    pv[cf] += __shfl_xor(pv[cf], 32);
  }
  if (lg == 0) {
#pragma unroll
    for (int cf = 0; cf < 2; ++cf)
      part[((size_t)b * 64 + rt) * 128 + ch + cf * 16 + l15] = pv[cf];
  }
}

// agg core (r16-verified): 32 rows x 128 cols per block, 512 threads. Wave wv =
// cf slice (cols wv*16..+16), FULL K (32 chunks), 2 row-sets; acc in regs (no
// accbuf, no mid-loop barriers); depth-2 B prefetch. ov[rs*4+j] = relu'd value
// for row r0 + rs*16 + lg*4 + j, col wv*16 + l15.
__device__ __forceinline__ void agg32_core(
    const u8* __restrict__ gpk, const u16* __restrict__ xF,
    const float* __restrict__ part, const float* __restrict__ sb,
    const int* __restrict__ mask, const float* __restrict__ nsadj, int b, int r0,
    int tid, float (*red)[128], float ov[8]) {
  {  // Vtot partials: 512 threads, 4 groups x 16 part-rows
    int col = tid & 127, grp = tid >> 7;
    float s = 0.f;
#pragma unroll
    for (int p = 0; p < 16; ++p)
      s += part[((size_t)b * 64 + grp * 16 + p) * 128 + col];
    red[grp][col] = s;
  }
  int wv = tid >> 6, lane = tid & 63;
  int l15 = lane & 15, lg = lane >> 4;

  // A bytes: 2 row-sets x 32 consecutive bytes (bytes lg*32+cl of each row)
  const u8* g0 = gpk + ((size_t)b * N + r0 + l15) * 128 + lg * 32;
  uint4 qA = *(const uint4*)g0;
  uint4 qB = *(const uint4*)(g0 + 16);
  uint4 qC = *(const uint4*)(g0 + 16 * 128);
  uint4 qD = *(const uint4*)(g0 + 16 * 128 + 16);
  u32 q0[8] = {qA.x, qA.y, qA.z, qA.w, qB.x, qB.y, qB.z, qB.w};
  u32 q1[8] = {qC.x, qC.y, qC.z, qC.w, qD.x, qD.y, qD.z, qD.w};

  // B base: xF[((b*8+wv)*32 + cl)*512 + lane*8], cl stride 512 elems
  const u16* xb = xF + (((size_t)b * 8 + wv) * 32) * 512 + lane * 8;

  float4v acc0 = {0.f, 0.f, 0.f, 0.f};
  float4v acc1 = {0.f, 0.f, 0.f, 0.f};
  short8v b0 = *(const short8v*)(xb);
  short8v b1 = *(const short8v*)(xb + 512);
#pragma unroll
  for (int cl = 0; cl < 32; ++cl) {
    short8v b2 = b0;  // placeholder for tail iterations
    if (cl + 2 < 32) b2 = *(const short8v*)(xb + (cl + 2) * 512);
    u32 by0 = (q0[cl >> 2] >> ((cl & 3) * 8)) & 255u;
    u32 by1 = (q1[cl >> 2] >> ((cl & 3) * 8)) & 255u;
    short8v a0 = expand_byte(by0);
    short8v a1 = expand_byte(by1);
    acc0 = __builtin_amdgcn_mfma_f32_16x16x32_bf16(a0, b0, acc0, 0, 0, 0);
    acc1 = __builtin_amdgcn_mfma_f32_16x16x32_bf16(a1, b0, acc1, 0, 0, 0);
    b0 = b1;
    b1 = b2;
  }
  __syncthreads();  // red ready for epilogue

  float sbv = sb[b];
  int col = wv * 16 + l15;
  float vt = red[0][col] + red[1][col] + red[2][col] + red[3][col];
#pragma unroll
  for (int rs = 0; rs < 2; ++rs) {
#pragma unroll
    for (int j = 0; j < 4; ++j) {
      float a = (rs == 0) ? acc0[j] : acc1[j];
      int orow = r0 + rs * 16 + lg * 4 + j;
      float nm = (float)mask[b * N + orow];
      float nnum = fmaxf(nm * (sbv - nm), 1.f);
      float inv = nm / nnum;
      size_t off = ((size_t)b * N + orow) * D + col;
      ov[rs * 4 + j] = fmaxf(nsadj[off] + inv * (a + vt), 0.f);
    }
  }
}

// XCD-aligned (b, rt32) for the 512-block agg kernels.
__device__ __forceinline__ void map_brt32(int blk, int& b, int& rt32) {
  int slot = blk >> 3;
  b = ((slot >> 5) << 3) | (blk & 7);
  rt32 = slot & 31;
}

// Co-dispatched: blocks 0..2047 graph bit-pack (hoisted loads); 2048..3071
// prep t=0.
__global__ __launch_bounds__(256, 4) void pack_prep_kernel(
    const float* __restrict__ node, const int* __restrict__ graph,
    const int* __restrict__ mask, const float* __restrict__ w_weight,
    const float* __restrict__ b_weight, const float* __restrict__ b_self,
    const u16* __restrict__ wsF, const u16* __restrict__ wlF,
    const u16* __restrict__ wrF, const float* __restrict__ sb,
    u8* __restrict__ gpk, float* __restrict__ outw, float* __restrict__ nsadjA,
    u16* __restrict__ xFA, float* __restrict__ partA) {
  __shared__ float nlds[16][132];
  __shared__ float wmrow[16], invrow[16];
  int tid = threadIdx.x;
  int blk = blockIdx.x;

  if (blk < 2048) {  // pack role: all loads issued before any store
    int gidx0 = blk * 256 + tid;
    int4 ra[4][2];
#pragma unroll
    for (int it = 0; it < 4; ++it) {
      int gidx = gidx0 + it * (2048 * 256);
      int j = gidx & 127, rowg = gidx >> 7;
      const int* gp = graph + ((size_t)rowg << 10) + j * 8;
      ra[it][0] = *(const int4*)gp;
      ra[it][1] = *(const int4*)(gp + 4);
    }
#pragma unroll
    for (int it = 0; it < 4; ++it) {
      int gidx = gidx0 + it * (2048 * 256);
      int j = gidx & 127, rowg = gidx >> 7;
      int i = rowg & (N - 1);
      int4 a = ra[it][0], c = ra[it][1];
      u32 by = (u32)(a.x != 0) | ((u32)(a.y != 0) << 1) | ((u32)(a.z != 0) << 2) |
               ((u32)(a.w != 0) << 3) | ((u32)(c.x != 0) << 4) |
               ((u32)(c.y != 0) << 5) | ((u32)(c.z != 0) << 6) |
               ((u32)(c.w != 0) << 7);
      if (j == (i >> 3)) by &= ~(1u << (i & 7));  // clear diagonal
      gpk[((size_t)rowg << 7) + (j & 3) * 32 + (j >> 2)] = (u8)by;
    }
    return;
  }

  int pblk = blk - 2048;  // 2048 % 8 == 0 -> XCD alignment preserved
  int b, rt;
  map_brt(pblk, b, rt);
  int r0 = rt * 16;

  const float* nbase = node + ((size_t)b * N + r0) * D;
#pragma unroll
  for (int p = 0; p < 2; ++p) {
    int g = p * 256 + tid;
    int row = g >> 5, c4 = g & 31;
    *(float4*)&nlds[row][c4 * 4] = *(const float4*)(nbase + row * 128 + c4 * 4);
  }
  __syncthreads();

  prep_body(nlds, wmrow, invrow, b, rt, tid, mask, w_weight, b_weight, b_self, wsF,
            wlF, wrF, sb, outw, nsadjA, xFA, partA);
}

// agg t=0 (A buffers) + prep t=1 (B buffers); out0 only in LDS. 512 threads:
// agg32 core, then both 16-row prep halves run in parallel (half = tid>>8).
__global__ __launch_bounds__(512, 4) void agg_prep_kernel(
    const u8* __restrict__ gpk, const int* __restrict__ mask,
    const float* __restrict__ w_weight, const float* __restrict__ b_weight,
    const float* __restrict__ b_self, const u16* __restrict__ wsF,
    const u16* __restrict__ wlF, const u16* __restrict__ wrF,
    const float* __restrict__ sb, const float* __restrict__ nsadjA,
    const u16* __restrict__ xFA, const float* __restrict__ partA,
    float* __restrict__ outw, float* __restrict__ nsadjB, u16* __restrict__ xFB,
    float* __restrict__ partB) {
  __shared__ float red[4][128];     // 2 KB
  __shared__ float nlds[32][132];   // 16.9 KB
  __shared__ float wmrow[32], invrow[32];
  int tid = threadIdx.x;
  int b, rt32;
  map_brt32(blockIdx.x, b, rt32);
  int r0 = rt32 * 32;

  float ov[8];
  agg32_core(gpk, xFA, partA, sb, mask, nsadjA, b, r0, tid, red, ov);

  int wv = tid >> 6, lane = tid & 63;
  int l15 = lane & 15, lg = lane >> 4;
  int col = wv * 16 + l15;
#pragma unroll
  for (int rs = 0; rs < 2; ++rs)
#pragma unroll
    for (int j = 0; j < 4; ++j) nlds[rs * 16 + lg * 4 + j][col] = ov[rs * 4 + j];
  __syncthreads();

  int half = tid >> 8;   // 0 or 1: which 16-row tile this half-block preps
  int tid2 = tid & 255;
  prep_body((float(*)[132]) & nlds[half * 16][0], &wmrow[half * 16],
            &invrow[half * 16], b, rt32 * 2 + half, tid2, mask, w_weight,
            b_weight, b_self, wsF, wlF, wrF, sb, outw + N, nsadjB, xFB, partB);
}

// agg t=1 -> final out (512 threads, agg32 core, direct stores).
__global__ __launch_bounds__(512, 4) void agg_fin_kernel(
    const u8* __restrict__ gpk, const int* __restrict__ mask,
    const float* __restrict__ sb, const float* __restrict__ nsadjB,
    const u16* __restrict__ xFB, const float* __restrict__ partB,
    float* __restrict__ out) {
  __shared__ float red[4][128];
  int tid = threadIdx.x;
  int b, rt32;
  map_brt32(blockIdx.x, b, rt32);
  int r0 = rt32 * 32;

  float ov[8];
  agg32_core(gpk, xFB, partB, sb, mask, nsadjB, b, r0, tid, red, ov);

  int wv = tid >> 6, lane = tid & 63;
  int l15 = lane & 15, lg = lane >> 4;
  int col = wv * 16 + l15;
#pragma unroll
  for (int rs = 0; rs < 2; ++rs)
#pragma unroll
    for (int j = 0; j < 4; ++j) {
      int orow = r0 + rs * 16 + lg * 4 + j;
      out[((size_t)b * N + orow) * D + col] = ov[rs * 4 + j];
    }
}

extern "C" void kernel_launch(void* const* d_in, const int* in_sizes, int n_in,
                              void* d_out, int out_size, void* d_ws, size_t ws_size,
                              hipStream_t stream) {
  const float* node0 = (const float*)d_in[0];
  const int* mask = (const int*)d_in[1];
  const int* graph = (const int*)d_in[2];
  const float* w_weight = (const float*)d_in[3];
  const float* b_weight = (const float*)d_in[4];
  const float* w_self = (const float*)d_in[5];
  const float* b_self = (const float*)d_in[6];
  const float* w_left = (const float*)d_in[7];
  const float* w_right = (const float*)d_in[8];
  float* out = (float*)d_out;
  float* outw = out + (size_t)B * N * D;  // all_node_weight [B,2,N]

  char* ws = (char*)d_ws;
  const size_t MB = 1024 * 1024;
  float* nsadjA = (float*)ws;                  // 8 MB
  float* nsadjB = (float*)(ws + 8 * MB);       // 8 MB
  u16* xFA = (u16*)(ws + 16 * MB);             // 4 MB
  u16* xFB = (u16*)(ws + 20 * MB);             // 4 MB
  u8* gpk = (u8*)(ws + 24 * MB);               // 2 MB
  u16* wsF = (u16*)(ws + 26 * MB);             // 3 x 32 KB
  u16* wlF = wsF + 16384;
  u16* wrF = wlF + 16384;
  float* partA = (float*)(ws + 26 * MB + 3 * 32768);  // 512 KB
  float* partB = partA + (size_t)B * 64 * 128;        // 512 KB
  float* sb = partB + (size_t)B * 64 * 128;

  wpack_kernel<<<13, 256, 0, stream>>>(w_self, w_left, w_right, mask, wsF, wlF,
                                       wrF, sb);
  pack_prep_kernel<<<3072, 256, 0, stream>>>(node0, graph, mask, w_weight,
                                             b_weight, b_self, wsF, wlF, wrF, sb,
                                             gpk, outw, nsadjA, xFA, partA);
  agg_prep_kernel<<<512, 512, 0, stream>>>(gpk, mask, w_weight, b_weight, b_self,
                                           wsF, wlF, wrF, sb, nsadjA, xFA, partA,
                                           outw, nsadjB, xFB, partB);
  agg_fin_kernel<<<512, 512, 0, stream>>>(gpk, mask, sb, nsadjB, xFB, partB, out);
}